// Round 8
// baseline (127.027 us; speedup 1.0000x reference)
//
#include <hip/hip_runtime.h>
#include <math.h>

#define VOCAB 32000
#define D 256
#define NB 32
#define NEQ 5
#define SEQ 64
#define NBASIS 96   // 32 bubbles + 64 token vectors

// ws layout (float offsets)
#define WS_S     0                          // [96][96] Gram of basis U=[B;X]
#define WS_COEF  (NBASIS*NBASIS)            // [SEQ][96] x_wm coefficients
#define WS_U     (WS_COEF + SEQ*NBASIS)     // [SEQ][NB]
#define WS_VV    (WS_U + SEQ*NB)            // [SEQ][NB]  (must stay right after WS_U)
#define WS_C     (WS_VV + SEQ*NB)           // [SEQ]
#define WS_XWM   (WS_C + SEQ)               // [SEQ][D]

typedef __attribute__((ext_vector_type(8))) short short8v;
typedef __attribute__((ext_vector_type(4))) float f32x4;

// ---------------------------------------------------------------------------
// K1: Gram matrix S[i][j] = u_i . u_j
// ---------------------------------------------------------------------------
__global__ __launch_bounds__(256) void foam_grams(
    const int* __restrict__ tokens, const float* __restrict__ E,
    const float* __restrict__ bubbles, float* __restrict__ ws)
{
    const int idx = blockIdx.x * 256 + threadIdx.x;   // < 9216
    const int i = idx / NBASIS, j = idx % NBASIS;
    const float4* ra = (const float4*)((i < NB) ? (bubbles + i * D)
                                                : (E + (long)tokens[i - NB] * D));
    const float4* rb = (const float4*)((j < NB) ? (bubbles + j * D)
                                                : (E + (long)tokens[j - NB] * D));
    float a0 = 0.f, a1 = 0.f, a2 = 0.f, a3 = 0.f;
    #pragma unroll
    for (int k = 0; k < D / 4; k += 4) {
        float4 x, y;
        x = ra[k];     y = rb[k];
        a0 = fmaf(x.x, y.x, fmaf(x.y, y.y, fmaf(x.z, y.z, fmaf(x.w, y.w, a0))));
        x = ra[k + 1]; y = rb[k + 1];
        a1 = fmaf(x.x, y.x, fmaf(x.y, y.y, fmaf(x.z, y.z, fmaf(x.w, y.w, a1))));
        x = ra[k + 2]; y = rb[k + 2];
        a2 = fmaf(x.x, y.x, fmaf(x.y, y.y, fmaf(x.z, y.z, fmaf(x.w, y.w, a2))));
        x = ra[k + 3]; y = rb[k + 3];
        a3 = fmaf(x.x, y.x, fmaf(x.y, y.y, fmaf(x.z, y.z, fmaf(x.w, y.w, a3))));
    }
    ws[WS_S + i * NBASIS + j] = (a0 + a1) + (a2 + a3);
}

// ---------------------------------------------------------------------------
// Fast cross-lane / math primitives — all VALU, no LDS pipe.
// ---------------------------------------------------------------------------
template <int CTRL>
__device__ __forceinline__ float dpp_add(float x) {
    int yi = __builtin_amdgcn_update_dpp(0, __float_as_int(x), CTRL, 0xF, 0xF, true);
    return x + __int_as_float(yi);
}
// x[l] + x[l^16]  (v_permlane16_swap_b32: swap 16-lane rows between 2 VGPRs)
__device__ __forceinline__ float xor16_add(float x) {
    float a, b;
    asm("v_mov_b32 %0, %2\n\t"
        "v_mov_b32 %1, %2\n\t"
        "v_permlane16_swap_b32 %0, %1"
        : "=&v"(a), "=&v"(b) : "v"(x));
    return a + b;
}
// x[l] + x[l^32]
__device__ __forceinline__ float xor32_add(float x) {
    float a, b;
    asm("v_mov_b32 %0, %2\n\t"
        "v_mov_b32 %1, %2\n\t"
        "v_permlane32_swap_b32 %0, %1"
        : "=&v"(a), "=&v"(b) : "v"(x));
    return a + b;
}
// full 64-lane sum in every lane: 4 row-local DPP adds + xor16 + xor32
__device__ __forceinline__ float sum64(float x) {
    x = dpp_add<0xB1>(x);    // quad_perm [1,0,3,2]  == xor 1
    x = dpp_add<0x4E>(x);    // quad_perm [2,3,0,1]  == xor 2
    x = dpp_add<0x124>(x);   // row_ror:4
    x = dpp_add<0x128>(x);   // row_ror:8  -> each row-of-16 has its row sum
    x = xor16_add(x);        // -> each 32-half has its half sum
    return xor32_add(x);     // -> full 64-lane sum
}
__device__ __forceinline__ float rdlane(float v, int lane) {
    return __int_as_float(__builtin_amdgcn_readlane(__float_as_int(v), lane));
}
__device__ __forceinline__ float fast_rcp(float x) {
    float r; asm("v_rcp_f32 %0, %1" : "=v"(r) : "v"(x)); return r;
}
__device__ __forceinline__ float fast_sqrt(float x) {
    float r; asm("v_sqrt_f32 %0, %1" : "=v"(r) : "v"(x)); return r;
}
__device__ __forceinline__ float fast_exp2(float x) {
    float r; asm("v_exp_f32 %0, %1" : "=v"(r) : "v"(x)); return r;
}

// ---------------------------------------------------------------------------
// K2: sequential scan, single wave, register state, all-VALU reductions.
// m coefs: m1 = coef[l] (all lanes); m2 = coef[32+l] (meaningful l>=32, else 0).
// xdm computed directly per token as a 96-dot (one sum64).
// ---------------------------------------------------------------------------
__global__ __launch_bounds__(64) void foam_scan4(
    const float* __restrict__ p_mdb, const float* __restrict__ p_ns,
    float* __restrict__ ws)
{
    const int l = threadIdx.x;
    const int b = l & 31;

    __shared__ float S2[SEQ][NBASIS];   // S2[t][i] = S[32+t][i]

    const float* wsS = ws + WS_S;
    for (int e = l; e < SEQ * NBASIS / 4; e += 64)
        ((float4*)S2)[e] = ((const float4*)(wsS + NB * NBASIS))[e];

    float gbb_row[NB];   // S[b][j], j<32
    {
        const float4* pa = (const float4*)(wsS + b * NBASIS);
        #pragma unroll
        for (int i = 0; i < 8; ++i) {
            float4 va = pa[i];
            gbb_row[4*i] = va.x; gbb_row[4*i+1] = va.y;
            gbb_row[4*i+2] = va.z; gbb_row[4*i+3] = va.w;
        }
    }
    const float diag = wsS[(NB + l) * NBASIS + NB + l];   // |x_l|^2
    const float bn2  = wsS[b * NBASIS + b];               // |bub_b|^2

    const float LOG2E = 1.44269504088896f;
    const float mdb2  = p_mdb[0] * LOG2E;
    const float sens2 = fabsf(p_ns[0]) * LOG2E;
    const float sl2e  = 0.0625f * LOG2E;

    __syncthreads();

    float y = 0.f, mm2 = 0.f;
    float m1 = 0.f, m2 = 0.f;

    float* wsCOEF = ws + WS_COEF;
    float* wsUV   = ws + WS_U;      // wsVV contiguous after
    float* wsC    = ws + WS_C;

    float gxcol = S2[0][b];         // bub_b . x_t
    float xcol1 = S2[0][l];         // x_t . u_l
    float xcol2 = S2[0][32 + l];    // x_t . u_{32+l}

    const int uvoff = (l >> 5) * (SEQ * NB);

    #pragma unroll 2
    for (int t = 0; t < SEQ; ++t) {
        // ---- xdm = x_t . mm  (direct 96-dot; m2 is 0 in lanes < 32) ----
        const float xdm = sum64(fmaf(xcol2, m2, xcol1 * m1));
        const float px  = rdlane(diag, t);
        const float nov = (mm2 > 9.8e-17f)
                        ? (1.f - xdm * fast_rcp(fast_sqrt(px * mm2)))
                        : 1.f;
        const float decay = fast_rcp(1.f + fast_exp2(fmaf(sens2, nov, -mdb2)));
        const float omd = 1.f - decay;

        // emit x_wm coefficients (OLD m)
        wsCOEF[t * NBASIS + l] = fmaf(decay, m1, (l == NB + t) ? 1.f : 0.f);
        if (l >= 32)
            wsCOEF[t * NBASIS + 32 + l] = fmaf(decay, m2, (l == t) ? 1.f : 0.f);

        const float q = px + 2.f * decay * xdm + decay * decay * mm2;
        const float c = fmaf(decay, y, gxcol);

        // prefetch next token's Gram columns (hidden under the rounds)
        const int tn = (t + 1) & (SEQ - 1);
        const float gxn = S2[tn][b];
        const float xn1 = S2[tn][l];
        const float xn2 = S2[tn][32 + l];

        // ---- 6 softmax rounds (exp2-domain; sum64 = 2*sum32 folded via ev+ev) ----
        const float cq2 = (c - q) * sl2e;
        const float qs2 = q * sl2e;
        float alpha = 1.f, w = 0.f;
        #pragma unroll
        for (int k = 0; k <= NEQ; ++k) {
            float ev = fast_exp2(fmaf(alpha, cq2, qs2));
            float r  = fast_rcp(sum64(ev));
            w = (ev + ev) * r;
            if (k < NEQ) alpha = fmaf(-alpha, w, alpha);
        }
        const float p = w;

        // ---- per-bubble outputs (uu in lanes<32, vv in lanes>=32; one store) ----
        const float oma = 1.f - alpha;
        const float s2v = alpha * alpha * bn2 + 2.f * alpha * oma * c + oma * oma * q;
        const float g = p * fast_rcp(s2v + 1e-20f);
        const float uu  = g * alpha * alpha;
        const float vv2 = 2.f * g * alpha * oma;
        wsUV[uvoff + t * NB + b] = (l < NB) ? uu : vv2;

        // ---- alpha broadcast (SGPRs) + G_BB . alpha matvec ----
        float asg[NB];
        #pragma unroll
        for (int j = 0; j < NB; ++j) asg[j] = rdlane(alpha, j);
        float ga0 = 0.f, ga1 = 0.f, ga2 = 0.f, ga3 = 0.f;
        #pragma unroll
        for (int j = 0; j < NB; j += 4) {
            ga0 = fmaf(gbb_row[j],     asg[j],     ga0);
            ga1 = fmaf(gbb_row[j + 1], asg[j + 1], ga1);
            ga2 = fmaf(gbb_row[j + 2], asg[j + 2], ga2);
            ga3 = fmaf(gbb_row[j + 3], asg[j + 3], ga3);
        }
        const float ga = (ga0 + ga1) + (ga2 + ga3);

        // ---- reductions over bubbles (values duplicated: sum64 = 2*sum32) ----
        const float r0 = sum64(alpha);
        const float r1 = sum64(alpha * c);
        const float r2 = sum64(alpha * y);
        const float r3 = sum64(alpha * ga);
        const float Cp = sum64(g * oma * oma);
        if (l == 0) wsC[t] = 0.5f * Cp;

        // ---- state update (scan2 algebra, constants rescaled for sum64) ----
        const float msc = (64.f - r0) * (1.f / 64.f);
        const float k1 = decay * fmaf(omd, msc, 1.f);
        const float mmxwm = fmaf(decay, mm2, xdm);
        const float mmms = fmaf(msc, mmxwm, r2 * (1.f / 64.f));
        const float u1sq = r3 * (1.f / 2048.f);
        const float msms = fmaf(msc * msc, q, fmaf(2.f * msc, r1 * (1.f / 64.f), u1sq));
        mm2 = decay * decay * mm2 + 2.f * decay * omd * mmms + omd * omd * msms;

        y = fmaf(k1, y, omd * fmaf(msc, gxcol, ga * (1.f / 32.f)));

        const float inc1 = (l < NB) ? omd * alpha * (1.f / 32.f)
                                    : ((l == NB + t) ? omd * msc : 0.f);
        m1 = fmaf(k1, m1, inc1);
        m2 = fmaf(k1, m2, (t >= NB && l == t) ? omd * msc : 0.f);

        gxcol = gxn;
        xcol1 = xn1;
        xcol2 = xn2;
    }
}

// ---------------------------------------------------------------------------
// K3: reconstruct x_wm[t][d]
// ---------------------------------------------------------------------------
__global__ __launch_bounds__(256) void foam_recon(
    const int* __restrict__ tokens, const float* __restrict__ E,
    const float* __restrict__ bubbles, float* __restrict__ ws)
{
    const int t = blockIdx.x;
    const int d = threadIdx.x;
    __shared__ float cf[NBASIS];
    __shared__ int stok[SEQ];
    if (d < NBASIS) cf[d] = ws[WS_COEF + t * NBASIS + d];
    if (d < SEQ) stok[d] = tokens[d];
    __syncthreads();
    float acc = 0.f;
    #pragma unroll 8
    for (int bb = 0; bb < NB; ++bb) acc = fmaf(cf[bb], bubbles[bb * D + d], acc);
    #pragma unroll 8
    for (int j = 0; j < SEQ; ++j) acc = fmaf(cf[32 + j], E[(long)stok[j] * D + d], acc);
    ws[WS_XWM + t * D + d] = acc;
}

// ---------------------------------------------------------------------------
// K4: MFMA split-bf16 GEMM H = E @ [bub; xwm]^T + fused Born-rule epilogue.
// ---------------------------------------------------------------------------
#define MROWS 32
#define HS 100
#define US 36

__device__ __forceinline__ void split_bf16(const float* p, short8v& hi, short8v& lo) {
    float4 f0 = *(const float4*)p;
    float4 f1 = *(const float4*)(p + 4);
    float f[8] = {f0.x, f0.y, f0.z, f0.w, f1.x, f1.y, f1.z, f1.w};
    #pragma unroll
    for (int j = 0; j < 8; ++j) {
        unsigned xb = __builtin_bit_cast(unsigned, f[j]);
        unsigned hb = xb & 0xFFFF0000u;
        float fl = f[j] - __builtin_bit_cast(float, hb);
        unsigned lb = __builtin_bit_cast(unsigned, fl);
        hi[j] = (short)(hb >> 16);
        lo[j] = (short)(lb >> 16);
    }
}

__global__ __launch_bounds__(512, 4) void foam_mfma_logits(
    const float* __restrict__ E,
    const float* __restrict__ bubbles,
    const float* __restrict__ ws,
    float* __restrict__ out)
{
    __shared__ float H[MROWS][HS];
    __shared__ float us[SEQ * US];
    __shared__ float vs[SEQ * US];
    __shared__ float Cs[SEQ];

    const int tid = threadIdx.x;
    const int w = tid >> 6;
    const int l = tid & 63;
    const int lm = l & 15;
    const int lq = l >> 4;

    for (int i = tid; i < SEQ * NB; i += 512) {
        int t = i >> 5, bb = i & 31;
        us[t * US + bb] = ws[WS_U + i];
        vs[t * US + bb] = ws[WS_VV + i];
    }
    if (tid < SEQ) Cs[tid] = ws[WS_C + tid];

    const long vb = (long)blockIdx.x * MROWS;

    if (w < 6) {
        short8v bhi[8], blo[8];
        const int n = w * 16 + lm;
        const float* wrow = (w < 2) ? (bubbles + n * D)
                                    : (ws + WS_XWM + (n - 32) * D);
        #pragma unroll
        for (int ks = 0; ks < 8; ++ks)
            split_bf16(wrow + ks * 32 + lq * 8, bhi[ks], blo[ks]);

        #pragma unroll
        for (int mt = 0; mt < 2; ++mt) {
            f32x4 acc = {0.f, 0.f, 0.f, 0.f};
            const float* arow = E + (vb + mt * 16 + lm) * D + lq * 8;
            #pragma unroll
            for (int ks = 0; ks < 8; ++ks) {
                short8v ahi, alo;
                split_bf16(arow + ks * 32, ahi, alo);
                acc = __builtin_amdgcn_mfma_f32_16x16x32_bf16(ahi, bhi[ks], acc, 0, 0, 0);
                acc = __builtin_amdgcn_mfma_f32_16x16x32_bf16(ahi, blo[ks], acc, 0, 0, 0);
                acc = __builtin_amdgcn_mfma_f32_16x16x32_bf16(alo, bhi[ks], acc, 0, 0, 0);
            }
            #pragma unroll
            for (int r = 0; r < 4; ++r)
                H[mt * 16 + lq * 4 + r][w * 16 + lm] = acc[r];
        }
    }
    __syncthreads();

    const int t0 = w * 8 + lq;
    const int t1 = t0 + 4;
    const float c0 = Cs[t0], c1 = Cs[t1];

    #pragma unroll
    for (int mt = 0; mt < 2; ++mt) {
        const int row = mt * 16 + lm;
        float G[NB], G2[NB];
        #pragma unroll
        for (int i = 0; i < 8; ++i)
            *(float4*)&G[4 * i] = *(const float4*)&H[row][4 * i];
        #pragma unroll
        for (int i = 0; i < NB; ++i) G2[i] = G[i] * G[i];

        float a0 = 0.f, b0 = 0.f, a1 = 0.f, b1 = 0.f;
        #pragma unroll
        for (int i = 0; i < 8; ++i) {
            float4 u0 = *(const float4*)&us[t0 * US + 4 * i];
            float4 v0 = *(const float4*)&vs[t0 * US + 4 * i];
            float4 u1 = *(const float4*)&us[t1 * US + 4 * i];
            float4 v1 = *(const float4*)&vs[t1 * US + 4 * i];
            a0 = fmaf(u0.x, G2[4*i], fmaf(u0.y, G2[4*i+1], fmaf(u0.z, G2[4*i+2], fmaf(u0.w, G2[4*i+3], a0))));
            b0 = fmaf(v0.x, G[4*i],  fmaf(v0.y, G[4*i+1],  fmaf(v0.z, G[4*i+2],  fmaf(v0.w, G[4*i+3],  b0))));
            a1 = fmaf(u1.x, G2[4*i], fmaf(u1.y, G2[4*i+1], fmaf(u1.z, G2[4*i+2], fmaf(u1.w, G2[4*i+3], a1))));
            b1 = fmaf(v1.x, G[4*i],  fmaf(v1.y, G[4*i+1],  fmaf(v1.z, G[4*i+2],  fmaf(v1.w, G[4*i+3],  b1))));
        }
        const float h0 = H[row][32 + t0];
        const float h1 = H[row][32 + t1];
        out[(long)t0 * VOCAB + vb + row] = fmaf(h0, b0, fmaf(h0 * h0, c0, a0));
        out[(long)t1 * VOCAB + vb + row] = fmaf(h1, b1, fmaf(h1 * h1, c1, a1));
    }
}

extern "C" void kernel_launch(void* const* d_in, const int* in_sizes, int n_in,
                              void* d_out, int out_size, void* d_ws, size_t ws_size,
                              hipStream_t stream) {
    const int*   tokens  = (const int*)d_in[0];
    const float* E       = (const float*)d_in[1];
    const float* bubbles = (const float*)d_in[2];
    const float* mdb     = (const float*)d_in[3];
    const float* ns      = (const float*)d_in[4];
    float* out = (float*)d_out;
    float* ws  = (float*)d_ws;

    hipLaunchKernelGGL(foam_grams, dim3((NBASIS * NBASIS) / 256), dim3(256), 0, stream,
                       tokens, E, bubbles, ws);
    hipLaunchKernelGGL(foam_scan4, dim3(1), dim3(64), 0, stream, mdb, ns, ws);
    hipLaunchKernelGGL(foam_recon, dim3(SEQ), dim3(256), 0, stream,
                       tokens, E, bubbles, ws);
    hipLaunchKernelGGL(foam_mfma_logits, dim3(VOCAB / MROWS), dim3(512), 0, stream,
                       E, bubbles, ws, out);
}

// Round 9
// 119.555 us; speedup vs baseline: 1.0625x; 1.0625x over previous
//
#include <hip/hip_runtime.h>
#include <math.h>

#define VOCAB 32000
#define D 256
#define NB 32
#define NEQ 5
#define SEQ 64
#define NBASIS 96   // 32 bubbles + 64 token vectors

// ws layout (float offsets)
#define WS_S     0                          // [96][96] Gram of basis U=[B;X]
#define WS_COEF  (NBASIS*NBASIS)            // [SEQ][96] x_wm coefficients
#define WS_U     (WS_COEF + SEQ*NBASIS)     // [SEQ][NB]
#define WS_VV    (WS_U + SEQ*NB)            // [SEQ][NB]  (must stay right after WS_U)
#define WS_C     (WS_VV + SEQ*NB)           // [SEQ]
#define WS_XWM   (WS_C + SEQ)               // [SEQ][D]

typedef __attribute__((ext_vector_type(8))) short short8v;
typedef __attribute__((ext_vector_type(4))) float f32x4;

// ---------------------------------------------------------------------------
// K1: Gram matrix S[i][j] = u_i . u_j
// ---------------------------------------------------------------------------
__global__ __launch_bounds__(256) void foam_grams(
    const int* __restrict__ tokens, const float* __restrict__ E,
    const float* __restrict__ bubbles, float* __restrict__ ws)
{
    const int idx = blockIdx.x * 256 + threadIdx.x;   // < 9216
    const int i = idx / NBASIS, j = idx % NBASIS;
    const float4* ra = (const float4*)((i < NB) ? (bubbles + i * D)
                                                : (E + (long)tokens[i - NB] * D));
    const float4* rb = (const float4*)((j < NB) ? (bubbles + j * D)
                                                : (E + (long)tokens[j - NB] * D));
    float a0 = 0.f, a1 = 0.f, a2 = 0.f, a3 = 0.f;
    #pragma unroll
    for (int k = 0; k < D / 4; k += 4) {
        float4 x, y;
        x = ra[k];     y = rb[k];
        a0 = fmaf(x.x, y.x, fmaf(x.y, y.y, fmaf(x.z, y.z, fmaf(x.w, y.w, a0))));
        x = ra[k + 1]; y = rb[k + 1];
        a1 = fmaf(x.x, y.x, fmaf(x.y, y.y, fmaf(x.z, y.z, fmaf(x.w, y.w, a1))));
        x = ra[k + 2]; y = rb[k + 2];
        a2 = fmaf(x.x, y.x, fmaf(x.y, y.y, fmaf(x.z, y.z, fmaf(x.w, y.w, a2))));
        x = ra[k + 3]; y = rb[k + 3];
        a3 = fmaf(x.x, y.x, fmaf(x.y, y.y, fmaf(x.z, y.z, fmaf(x.w, y.w, a3))));
    }
    ws[WS_S + i * NBASIS + j] = (a0 + a1) + (a2 + a3);
}

// ---------------------------------------------------------------------------
// Fast cross-lane / math primitives — all VALU, no LDS pipe.
// ---------------------------------------------------------------------------
template <int CTRL>
__device__ __forceinline__ float dpp_add(float x) {
    int yi = __builtin_amdgcn_update_dpp(0, __float_as_int(x), CTRL, 0xF, 0xF, true);
    return x + __int_as_float(yi);
}
// x[l] + x[l^16]
__device__ __forceinline__ float xor16_add(float x) {
    float a, b;
    asm("v_mov_b32 %0, %2\n\t"
        "v_mov_b32 %1, %2\n\t"
        "v_permlane16_swap_b32 %0, %1"
        : "=&v"(a), "=&v"(b) : "v"(x));
    return a + b;
}
// x[l] + x[l^32]
__device__ __forceinline__ float xor32_add(float x) {
    float a, b;
    asm("v_mov_b32 %0, %2\n\t"
        "v_mov_b32 %1, %2\n\t"
        "v_permlane32_swap_b32 %0, %1"
        : "=&v"(a), "=&v"(b) : "v"(x));
    return a + b;
}
// sum over each 32-lane half (valid as 32-bubble sum when halves duplicated)
__device__ __forceinline__ float sum32h(float x) {
    x = dpp_add<0xB1>(x);    // xor 1
    x = dpp_add<0x4E>(x);    // xor 2
    x = dpp_add<0x124>(x);   // row_ror:4
    x = dpp_add<0x128>(x);   // row_ror:8  -> row-of-16 sums
    return xor16_add(x);     // -> 32-half sum
}
// full 64-lane sum
__device__ __forceinline__ float sum64(float x) {
    return xor32_add(sum32h(x));
}
__device__ __forceinline__ float rdlane(float v, int lane) {
    return __int_as_float(__builtin_amdgcn_readlane(__float_as_int(v), lane));
}
__device__ __forceinline__ float fast_rcp(float x) {
    float r; asm("v_rcp_f32 %0, %1" : "=v"(r) : "v"(x)); return r;
}
__device__ __forceinline__ float fast_sqrt(float x) {
    float r; asm("v_sqrt_f32 %0, %1" : "=v"(r) : "v"(x)); return r;
}
__device__ __forceinline__ float fast_exp2(float x) {
    float r; asm("v_exp_f32 %0, %1" : "=v"(r) : "v"(x)); return r;
}

// ---------------------------------------------------------------------------
// K2: sequential scan, single wave, register state, all-VALU reductions.
// Bubble-side quantities duplicated across halves -> 5-stage sum32h.
// Softmax rounds use shift-invariance (uniform q*scale dropped).
// ---------------------------------------------------------------------------
__global__ __launch_bounds__(64) void foam_scan5(
    const float* __restrict__ p_mdb, const float* __restrict__ p_ns,
    float* __restrict__ ws)
{
    const int l = threadIdx.x;
    const int b = l & 31;

    __shared__ float S2[SEQ][NBASIS];   // S2[t][i] = S[32+t][i]

    const float* wsS = ws + WS_S;
    for (int e = l; e < SEQ * NBASIS / 4; e += 64)
        ((float4*)S2)[e] = ((const float4*)(wsS + NB * NBASIS))[e];

    float gbb_row[NB];   // S[b][j], j<32
    {
        const float4* pa = (const float4*)(wsS + b * NBASIS);
        #pragma unroll
        for (int i = 0; i < 8; ++i) {
            float4 va = pa[i];
            gbb_row[4*i] = va.x; gbb_row[4*i+1] = va.y;
            gbb_row[4*i+2] = va.z; gbb_row[4*i+3] = va.w;
        }
    }
    const float diag = wsS[(NB + l) * NBASIS + NB + l];   // |x_l|^2
    const float bn2  = wsS[b * NBASIS + b];               // |bub_b|^2

    const float LOG2E = 1.44269504088896f;
    const float mdb2  = p_mdb[0] * LOG2E;
    const float sens2 = fabsf(p_ns[0]) * LOG2E;
    const float sl2e  = 0.0625f * LOG2E;

    __syncthreads();

    float y = 0.f, mm2 = 0.f;
    float m1 = 0.f, m2 = 0.f;   // coef[l]; coef[32+l] (meaningful l>=32, else 0)

    float* wsCOEF = ws + WS_COEF;
    float* wsUV   = ws + WS_U;      // wsVV contiguous after
    float* wsC    = ws + WS_C;

    float gxcol = S2[0][b];         // bub_b . x_t
    float xcol1 = S2[0][l];         // x_t . u_l
    float xcol2 = S2[0][32 + l];    // x_t . u_{32+l}

    const int uvoff = (l >> 5) * (SEQ * NB);

    #pragma unroll 2
    for (int t = 0; t < SEQ; ++t) {
        // ---- xdm = x_t . mm  (true 96-dot across 64 lanes; m2 zero in lanes<32) ----
        const float xdm = sum64(fmaf(xcol2, m2, xcol1 * m1));
        const float px  = rdlane(diag, t);
        const float nov = (mm2 > 9.8e-17f)
                        ? (1.f - xdm * fast_rcp(fast_sqrt(px * mm2)))
                        : 1.f;
        const float decay = fast_rcp(1.f + fast_exp2(fmaf(sens2, nov, -mdb2)));
        const float omd = 1.f - decay;

        // emit x_wm coefficients (OLD m)
        wsCOEF[t * NBASIS + l] = fmaf(decay, m1, (l == NB + t) ? 1.f : 0.f);
        if (l >= 32)
            wsCOEF[t * NBASIS + 32 + l] = fmaf(decay, m2, (l == t) ? 1.f : 0.f);

        const float q = px + 2.f * decay * xdm + decay * decay * mm2;
        const float c = fmaf(decay, y, gxcol);

        // prefetch next token's Gram columns (hidden under the rounds)
        const int tn = (t + 1) & (SEQ - 1);
        const float gxn = S2[tn][b];
        const float xn1 = S2[tn][l];
        const float xn2 = S2[tn][32 + l];

        // ---- 6 softmax rounds; uniform q*scale shift cancels in softmax ----
        const float cq2 = (c - q) * sl2e;
        float alpha = 1.f, p = 0.f;
        #pragma unroll
        for (int k = 0; k <= NEQ; ++k) {
            const float ev = fast_exp2(alpha * cq2);
            const float sm = sum32h(ev);
            const float r  = fast_rcp(sm);
            if (k < NEQ) {
                const float ae = alpha * ev;       // parallel with rcp
                alpha = fmaf(-ae, r, alpha);
            } else {
                p = ev * r;
            }
        }

        // ---- per-bubble outputs (uu in lanes<32, vv in lanes>=32; one store) ----
        const float oma = 1.f - alpha;
        const float s2v = alpha * alpha * bn2 + 2.f * alpha * oma * c + oma * oma * q;
        const float g = p * fast_rcp(s2v + 1e-20f);
        const float uu  = g * alpha * alpha;
        const float vv2 = 2.f * g * alpha * oma;
        wsUV[uvoff + t * NB + b] = (l < NB) ? uu : vv2;

        // ---- alpha broadcast (SGPRs) + G_BB . alpha matvec ----
        float asg[NB];
        #pragma unroll
        for (int j = 0; j < NB; ++j) asg[j] = rdlane(alpha, j);
        float ga0 = 0.f, ga1 = 0.f, ga2 = 0.f, ga3 = 0.f;
        #pragma unroll
        for (int j = 0; j < NB; j += 4) {
            ga0 = fmaf(gbb_row[j],     asg[j],     ga0);
            ga1 = fmaf(gbb_row[j + 1], asg[j + 1], ga1);
            ga2 = fmaf(gbb_row[j + 2], asg[j + 2], ga2);
            ga3 = fmaf(gbb_row[j + 3], asg[j + 3], ga3);
        }
        const float ga = (ga0 + ga1) + (ga2 + ga3);

        // ---- reductions over bubbles (duplicated halves -> sum32h) ----
        const float r0 = sum32h(alpha);
        const float r1 = sum32h(alpha * c);
        const float r2 = sum32h(alpha * y);
        const float r3 = sum32h(alpha * ga);
        const float Cp = sum32h(g * oma * oma);
        if (l == 0) wsC[t] = Cp;

        // ---- state update (verified scan2/scan3 algebra & constants) ----
        const float msc = (32.f - r0) * (1.f / 32.f);
        const float k1 = decay * fmaf(omd, msc, 1.f);
        const float mmxwm = fmaf(decay, mm2, xdm);
        const float mmms = fmaf(msc, mmxwm, r2 * (1.f / 32.f));
        const float u1sq = r3 * (1.f / 1024.f);
        const float msms = fmaf(msc * msc, q, fmaf(2.f * msc, r1 * (1.f / 32.f), u1sq));
        mm2 = decay * decay * mm2 + 2.f * decay * omd * mmms + omd * omd * msms;

        y = fmaf(k1, y, omd * fmaf(msc, gxcol, ga * (1.f / 32.f)));

        const float inc1 = (l < NB) ? omd * alpha * (1.f / 32.f)
                                    : ((l == NB + t) ? omd * msc : 0.f);
        m1 = fmaf(k1, m1, inc1);
        m2 = fmaf(k1, m2, (t >= NB && l == t) ? omd * msc : 0.f);

        gxcol = gxn;
        xcol1 = xn1;
        xcol2 = xn2;
    }
}

// ---------------------------------------------------------------------------
// K3: reconstruct x_wm[t][d]
// ---------------------------------------------------------------------------
__global__ __launch_bounds__(256) void foam_recon(
    const int* __restrict__ tokens, const float* __restrict__ E,
    const float* __restrict__ bubbles, float* __restrict__ ws)
{
    const int t = blockIdx.x;
    const int d = threadIdx.x;
    __shared__ float cf[NBASIS];
    __shared__ int stok[SEQ];
    if (d < NBASIS) cf[d] = ws[WS_COEF + t * NBASIS + d];
    if (d < SEQ) stok[d] = tokens[d];
    __syncthreads();
    float acc = 0.f;
    #pragma unroll 8
    for (int bb = 0; bb < NB; ++bb) acc = fmaf(cf[bb], bubbles[bb * D + d], acc);
    #pragma unroll 8
    for (int j = 0; j < SEQ; ++j) acc = fmaf(cf[32 + j], E[(long)stok[j] * D + d], acc);
    ws[WS_XWM + t * D + d] = acc;
}

// ---------------------------------------------------------------------------
// K4: MFMA split-bf16 GEMM H = E @ [bub; xwm]^T + fused Born-rule epilogue.
// ---------------------------------------------------------------------------
#define MROWS 32
#define HS 100
#define US 36

__device__ __forceinline__ void split_bf16(const float* p, short8v& hi, short8v& lo) {
    float4 f0 = *(const float4*)p;
    float4 f1 = *(const float4*)(p + 4);
    float f[8] = {f0.x, f0.y, f0.z, f0.w, f1.x, f1.y, f1.z, f1.w};
    #pragma unroll
    for (int j = 0; j < 8; ++j) {
        unsigned xb = __builtin_bit_cast(unsigned, f[j]);
        unsigned hb = xb & 0xFFFF0000u;
        float fl = f[j] - __builtin_bit_cast(float, hb);
        unsigned lb = __builtin_bit_cast(unsigned, fl);
        hi[j] = (short)(hb >> 16);
        lo[j] = (short)(lb >> 16);
    }
}

__global__ __launch_bounds__(512, 4) void foam_mfma_logits(
    const float* __restrict__ E,
    const float* __restrict__ bubbles,
    const float* __restrict__ ws,
    float* __restrict__ out)
{
    __shared__ float H[MROWS][HS];
    __shared__ float us[SEQ * US];
    __shared__ float vs[SEQ * US];
    __shared__ float Cs[SEQ];

    const int tid = threadIdx.x;
    const int w = tid >> 6;
    const int l = tid & 63;
    const int lm = l & 15;
    const int lq = l >> 4;

    for (int i = tid; i < SEQ * NB; i += 512) {
        int t = i >> 5, bb = i & 31;
        us[t * US + bb] = ws[WS_U + i];
        vs[t * US + bb] = ws[WS_VV + i];
    }
    if (tid < SEQ) Cs[tid] = ws[WS_C + tid];

    const long vb = (long)blockIdx.x * MROWS;

    if (w < 6) {
        short8v bhi[8], blo[8];
        const int n = w * 16 + lm;
        const float* wrow = (w < 2) ? (bubbles + n * D)
                                    : (ws + WS_XWM + (n - 32) * D);
        #pragma unroll
        for (int ks = 0; ks < 8; ++ks)
            split_bf16(wrow + ks * 32 + lq * 8, bhi[ks], blo[ks]);

        #pragma unroll
        for (int mt = 0; mt < 2; ++mt) {
            f32x4 acc = {0.f, 0.f, 0.f, 0.f};
            const float* arow = E + (vb + mt * 16 + lm) * D + lq * 8;
            #pragma unroll
            for (int ks = 0; ks < 8; ++ks) {
                short8v ahi, alo;
                split_bf16(arow + ks * 32, ahi, alo);
                acc = __builtin_amdgcn_mfma_f32_16x16x32_bf16(ahi, bhi[ks], acc, 0, 0, 0);
                acc = __builtin_amdgcn_mfma_f32_16x16x32_bf16(ahi, blo[ks], acc, 0, 0, 0);
                acc = __builtin_amdgcn_mfma_f32_16x16x32_bf16(alo, bhi[ks], acc, 0, 0, 0);
            }
            #pragma unroll
            for (int r = 0; r < 4; ++r)
                H[mt * 16 + lq * 4 + r][w * 16 + lm] = acc[r];
        }
    }
    __syncthreads();

    const int t0 = w * 8 + lq;
    const int t1 = t0 + 4;
    const float c0 = Cs[t0], c1 = Cs[t1];

    #pragma unroll
    for (int mt = 0; mt < 2; ++mt) {
        const int row = mt * 16 + lm;
        float G[NB], G2[NB];
        #pragma unroll
        for (int i = 0; i < 8; ++i)
            *(float4*)&G[4 * i] = *(const float4*)&H[row][4 * i];
        #pragma unroll
        for (int i = 0; i < NB; ++i) G2[i] = G[i] * G[i];

        float a0 = 0.f, b0 = 0.f, a1 = 0.f, b1 = 0.f;
        #pragma unroll
        for (int i = 0; i < 8; ++i) {
            float4 u0 = *(const float4*)&us[t0 * US + 4 * i];
            float4 v0 = *(const float4*)&vs[t0 * US + 4 * i];
            float4 u1 = *(const float4*)&us[t1 * US + 4 * i];
            float4 v1 = *(const float4*)&vs[t1 * US + 4 * i];
            a0 = fmaf(u0.x, G2[4*i], fmaf(u0.y, G2[4*i+1], fmaf(u0.z, G2[4*i+2], fmaf(u0.w, G2[4*i+3], a0))));
            b0 = fmaf(v0.x, G[4*i],  fmaf(v0.y, G[4*i+1],  fmaf(v0.z, G[4*i+2],  fmaf(v0.w, G[4*i+3],  b0))));
            a1 = fmaf(u1.x, G2[4*i], fmaf(u1.y, G2[4*i+1], fmaf(u1.z, G2[4*i+2], fmaf(u1.w, G2[4*i+3], a1))));
            b1 = fmaf(v1.x, G[4*i],  fmaf(v1.y, G[4*i+1],  fmaf(v1.z, G[4*i+2],  fmaf(v1.w, G[4*i+3],  b1))));
        }
        const float h0 = H[row][32 + t0];
        const float h1 = H[row][32 + t1];
        out[(long)t0 * VOCAB + vb + row] = fmaf(h0, b0, fmaf(h0 * h0, c0, a0));
        out[(long)t1 * VOCAB + vb + row] = fmaf(h1, b1, fmaf(h1 * h1, c1, a1));
    }
}

extern "C" void kernel_launch(void* const* d_in, const int* in_sizes, int n_in,
                              void* d_out, int out_size, void* d_ws, size_t ws_size,
                              hipStream_t stream) {
    const int*   tokens  = (const int*)d_in[0];
    const float* E       = (const float*)d_in[1];
    const float* bubbles = (const float*)d_in[2];
    const float* mdb     = (const float*)d_in[3];
    const float* ns      = (const float*)d_in[4];
    float* out = (float*)d_out;
    float* ws  = (float*)d_ws;

    hipLaunchKernelGGL(foam_grams, dim3((NBASIS * NBASIS) / 256), dim3(256), 0, stream,
                       tokens, E, bubbles, ws);
    hipLaunchKernelGGL(foam_scan5, dim3(1), dim3(64), 0, stream, mdb, ns, ws);
    hipLaunchKernelGGL(foam_recon, dim3(SEQ), dim3(256), 0, stream,
                       tokens, E, bubbles, ws);
    hipLaunchKernelGGL(foam_mfma_logits, dim3(VOCAB / MROWS), dim3(512), 0, stream,
                       E, bubbles, ws, out);
}